// Round 12
// baseline (270.045 us; speedup 1.0000x reference)
//
#include <hip/hip_runtime.h>
#include <hip/hip_bf16.h>
#include <math.h>

// Problem constants
#define BB      4
#define NN      2048
#define DM      768
#define NH      8
#define DHH     96
#define BH      (BB*NH)          // 32
#define MROWS   (BB*NN)          // 8192
#define NC_QKV  (3*DM)           // 2304

typedef short v4s  __attribute__((ext_vector_type(4)));
typedef short v8s  __attribute__((ext_vector_type(8)));
typedef float v4f  __attribute__((ext_vector_type(4)));
typedef float v16f __attribute__((ext_vector_type(16)));
typedef unsigned int u32;

// log2(e)/sqrt(96) folded into Q at QKV-GEMM epilogue
#define SCQ 0.14724599350930152f

static __device__ __forceinline__ ushort f2bf(float f) {
    __hip_bfloat16 h = __float2bfloat16(f);
    return *reinterpret_cast<ushort*>(&h);
}

static __device__ __forceinline__ void gload_lds16(const ushort* g, ushort* l) {
    __builtin_amdgcn_global_load_lds(
        (const __attribute__((address_space(1))) void*)g,
        (__attribute__((address_space(3))) void*)l, 16, 0, 0);
}

// two 8B LDS loads 32B apart -> one v8s A-fragment (k-permutation pi)
static __device__ __forceinline__ v8s load2x4_o16(const ushort* p) {
    union { v4s h[2]; v8s s; } x;
    x.h[0] = *reinterpret_cast<const v4s*>(p);
    x.h[1] = *reinterpret_cast<const v4s*>(p + 16);
    return x.s;
}

static __device__ __forceinline__ v8s pack4(u32 a, u32 b, u32 c, u32 d) {
    union { u32 u[4]; v8s s; } x;
    x.u[0] = a; x.u[1] = b; x.u[2] = c; x.u[3] = d;
    return x.s;
}
static __device__ __forceinline__ u32 bfpair(float lo, float hi) {
    return (u32)f2bf(lo) | ((u32)f2bf(hi) << 16);
}

// ---------------------------------------------------------------------------
// fp32 -> bf16 elementwise (n8 = count/8)
// ---------------------------------------------------------------------------
__global__ __launch_bounds__(256)
void conv_bf16(const float* __restrict__ in, ushort* __restrict__ out, int n8)
{
    int i = blockIdx.x * 256 + threadIdx.x;
    if (i >= n8) return;
    const float4* p = reinterpret_cast<const float4*>(in) + (size_t)i * 2;
    float4 a = p[0], b = p[1];
    ushort r[8] = {f2bf(a.x), f2bf(a.y), f2bf(a.z), f2bf(a.w),
                   f2bf(b.x), f2bf(b.y), f2bf(b.z), f2bf(b.w)};
    *reinterpret_cast<v8s*>(out + (size_t)i * 8) = *reinterpret_cast<v8s*>(r);
}

// ---------------------------------------------------------------------------
// fp32 W[K][N] -> bf16 Wt[N][K] (tiled transpose)
// ---------------------------------------------------------------------------
__global__ __launch_bounds__(256)
void convT_bf16(const float* __restrict__ W, ushort* __restrict__ Wt, int K, int N)
{
    __shared__ ushort t[32][33];
    const int k0 = blockIdx.x * 32, n0 = blockIdx.y * 32;
    const int tx = threadIdx.x & 31, ty = threadIdx.x >> 5;
    #pragma unroll
    for (int r = ty; r < 32; r += 8)
        t[tx][r] = f2bf(W[(size_t)(k0 + r) * N + n0 + tx]);
    __syncthreads();
    #pragma unroll
    for (int r = ty; r < 32; r += 8)
        Wt[(size_t)(n0 + r) * K + k0 + tx] = t[r][tx];
}

// ---------------------------------------------------------------------------
// bf16 MFMA GEMM (round-6/7 form, harness-proven, unchanged)
// ---------------------------------------------------------------------------
template<int SCATTER>
__global__ __launch_bounds__(256)
void gemm_mfma(const ushort* __restrict__ A, const ushort* __restrict__ Bt,
               const float* __restrict__ bias, void* __restrict__ outp,
               int K, int Ncols)
{
    __shared__ ushort As[2][8192];   // [buf][8 kslots][128 rows][8]
    __shared__ ushort Bs[2][8192];

    const int tid  = threadIdx.x;
    const int lane = tid & 63;
    const int wv   = tid >> 6;
    const int l31  = lane & 31;
    const int lhi  = lane >> 5;
    const int wr   = wv >> 1, wc = wv & 1;

    const int ny   = gridDim.y;
    const int id   = blockIdx.y * gridDim.x + blockIdx.x;
    const int c8   = id & 7;
    const int j    = id >> 3;
    const int hy   = (j >= (ny >> 1) * 8) ? 1 : 0;
    const int w    = j - hy * (ny >> 1) * 8;
    const int bx   = c8 * 8 + (w & 7);
    const int by   = hy * (ny >> 1) + (w >> 3);
    const int row0 = bx * 128;
    const int col0 = by * 128;

    v16f acc[2][2];
    #pragma unroll
    for (int mi = 0; mi < 2; ++mi)
        #pragma unroll
        for (int nj = 0; nj < 2; ++nj)
            #pragma unroll
            for (int i = 0; i < 16; ++i) acc[mi][nj][i] = 0.0f;

#define STAGE_G(bsel, kk) do {                                                  \
    _Pragma("unroll")                                                           \
    for (int c = 0; c < 4; ++c) {                                               \
        const int g   = c * 4 + wv;                                             \
        const int idx = g * 64 + lane;                                          \
        const int ss  = idx >> 7, rr = idx & 127;                               \
        gload_lds16(&A [(size_t)(row0 + rr) * K + (kk) + ss * 8],               \
                    &As[bsel][g * 512]);                                        \
        gload_lds16(&Bt[(size_t)(col0 + rr) * K + (kk) + ss * 8],               \
                    &Bs[bsel][g * 512]);                                        \
    }                                                                           \
} while (0)

    STAGE_G(0, 0);
    __syncthreads();

    const int nk = K >> 6;
    for (int t = 0; t < nk; ++t) {
        const int cur = t & 1;
        if (t + 1 < nk) STAGE_G(cur ^ 1, (t + 1) << 6);

        #pragma unroll
        for (int s16 = 0; s16 < 4; ++s16) {
            const int ks = s16 * 2 + lhi;
            v8s a0 = *reinterpret_cast<const v8s*>(&As[cur][(size_t)(ks * 128 + 64 * wr + l31) * 8]);
            v8s a1 = *reinterpret_cast<const v8s*>(&As[cur][(size_t)(ks * 128 + 64 * wr + 32 + l31) * 8]);
            v8s b0 = *reinterpret_cast<const v8s*>(&Bs[cur][(size_t)(ks * 128 + 64 * wc + l31) * 8]);
            v8s b1 = *reinterpret_cast<const v8s*>(&Bs[cur][(size_t)(ks * 128 + 64 * wc + 32 + l31) * 8]);
            acc[0][0] = __builtin_amdgcn_mfma_f32_32x32x16_bf16(a0, b0, acc[0][0], 0, 0, 0);
            acc[0][1] = __builtin_amdgcn_mfma_f32_32x32x16_bf16(a0, b1, acc[0][1], 0, 0, 0);
            acc[1][0] = __builtin_amdgcn_mfma_f32_32x32x16_bf16(a1, b0, acc[1][0], 0, 0, 0);
            acc[1][1] = __builtin_amdgcn_mfma_f32_32x32x16_bf16(a1, b1, acc[1][1], 0, 0, 0);
        }
        __syncthreads();
    }
#undef STAGE_G

    #pragma unroll
    for (int nj = 0; nj < 2; ++nj) {
        const int c = col0 + 64 * wc + 32 * nj + l31;
        const float bv = bias[c];
        #pragma unroll
        for (int mi = 0; mi < 2; ++mi) {
            #pragma unroll
            for (int r = 0; r < 16; ++r) {
                const int m = row0 + 64 * wr + 32 * mi + (r & 3) + 8 * (r >> 2) + 4 * lhi;
                float v = acc[mi][nj][r] + bv;
                if (SCATTER) {
                    const int s   = c / DM;
                    const int rem = c - s * DM;
                    const int h   = rem / DHH;
                    const int d   = rem - h * DHH;
                    const int b   = m >> 11;
                    const int n   = m & (NN - 1);
                    if (s == 0) v *= SCQ;
                    ((ushort*)outp)[((size_t)(s * BH + b * NH + h) * NN + n) * DHH + d] = f2bf(v);
                } else {
                    ((float*)outp)[(size_t)m * Ncols + c] = v;
                }
            }
        }
    }
}

// ---------------------------------------------------------------------------
// MFMA bf16 flash attention, kv-split waves (DS-pipe-optimized).
// Block = 64 q rows x one bh; 4 waves; tile = 128 kv; wave wv owns kv slice
// [wv*32, wv*32+32). Each wave computes S^T for ALL 64 q over its slice
// (Q B-frags for 4 q-tiles in registers -> K-frag reads drop 4x), then
// partial O over its slice; cross-wave O reduction once per block via LDS.
// All MFMA = verified 16x16x32 mappings (A: k=(l>>4)*8+i, B: col=l15,
// C: col=l15,row=(l>>4)*4+r). PV uses k-permutation pi(g4,i)=g4*4+(i&3)+
// 16*(i>>2) shared by P-pack and V^T reads (load2x4_o16, r7/r11-proven).
// V transposed in REGISTERS at staging (8kv x 8d -> b128 writes, replacing
// 24 ds_write_b16). Single-buffer handoff, 3 barriers/tile.
// ---------------------------------------------------------------------------
#define VTB 12288          // Vt base (ushort idx): after Ks[12][128][8]
#define DSB 6400           // dsm base (float idx) in epilogue overlay

__global__ __launch_bounds__(256, 2)
void attn_mfma(const ushort* __restrict__ qkv, ushort* __restrict__ attnout)
{
    // union: stage { Ks[12][128][8] | Vt[96][136] }  /  epi { Of f32[64][100], dsm f32[4][64] }
    __shared__ ushort smem[25344];   // 50688 B

    const int tid  = threadIdx.x;
    const int lane = tid & 63;
    const int wv   = tid >> 6;      // 0..3 : kv slice owner
    const int l15  = lane & 15;
    const int g4   = lane >> 4;     // 0..3

    // bh-clustered XCD swizzle (grid = (32, 32))
    const int id   = blockIdx.y * gridDim.x + blockIdx.x;
    const int c8   = id & 7;
    const int j    = id >> 3;        // 0..127
    const int bh   = c8 * 4 + (j & 3);
    const int qblk = j >> 2;         // 0..31
    const int q0   = qblk * 64;
    const int b    = bh >> 3, h = bh & 7;

    const ushort* Qg = qkv + (size_t)bh * NN * DHH;
    const ushort* Kg = qkv + ((size_t)BH + bh) * NN * DHH;
    const ushort* Vg = qkv + ((size_t)2 * BH + bh) * NN * DHH;

    // Q B-frags (pre-scaled by SCQ): qf[qt][c] = Q[q0+qt*16+l15][c*32+g4*8..+7]
    v8s qf[4][3];
    #pragma unroll
    for (int qt = 0; qt < 4; ++qt)
        #pragma unroll
        for (int c = 0; c < 3; ++c)
            qf[qt][c] = *reinterpret_cast<const v8s*>(
                &Qg[(size_t)(q0 + qt * 16 + l15) * DHH + c * 32 + g4 * 8]);

    v4f of[6][4];
    #pragma unroll
    for (int dt = 0; dt < 6; ++dt)
        #pragma unroll
        for (int qt = 0; qt < 4; ++qt)
            #pragma unroll
            for (int i = 0; i < 4; ++i) of[dt][qt][i] = 0.0f;
    float ds4[4] = {0.0f, 0.0f, 0.0f, 0.0f};

    // staging offsets
    int kgo[6], klo[6];
    #pragma unroll
    for (int i = 0; i < 6; ++i) {
        const int u = i * 256 + tid;          // 0..1535
        const int r = u / 12, c = u - r * 12; // K row / d-octet
        kgo[i] = r * DHH + c * 8;
        klo[i] = (c * 128 + r) * 8;
    }
    const int  kvb = (tid & 15) * 8;          // V: 8-kv block
    const int  dg  = tid >> 4;                // V: d-octet (valid tid<192)
    const size_t vgo = (size_t)kvb * DHH + dg * 8;
    const int  vlo = VTB + dg * 8 * 136 + kvb;

    // ---- prologue: stage tile 0
    {
        v8s kr[6];
        #pragma unroll
        for (int i = 0; i < 6; ++i)
            kr[i] = *reinterpret_cast<const v8s*>(&Kg[kgo[i]]);
        v8s vr[8];
        if (tid < 192) {
            #pragma unroll
            for (int r = 0; r < 8; ++r)
                vr[r] = *reinterpret_cast<const v8s*>(&Vg[vgo + (size_t)r * DHH]);
        }
        #pragma unroll
        for (int i = 0; i < 6; ++i)
            *reinterpret_cast<v8s*>(&smem[klo[i]]) = kr[i];
        if (tid < 192) {
            #pragma unroll
            for (int j8 = 0; j8 < 8; ++j8) {
                u32 w0 = (u32)(ushort)vr[0][j8] | ((u32)(ushort)vr[1][j8] << 16);
                u32 w1 = (u32)(ushort)vr[2][j8] | ((u32)(ushort)vr[3][j8] << 16);
                u32 w2 = (u32)(ushort)vr[4][j8] | ((u32)(ushort)vr[5][j8] << 16);
                u32 w3 = (u32)(ushort)vr[6][j8] | ((u32)(ushort)vr[7][j8] << 16);
                *reinterpret_cast<v8s*>(&smem[vlo + j8 * 136]) = pack4(w0, w1, w2, w3);
            }
        }
    }
    __syncthreads();

    for (int t = 0; t < 16; ++t) {
        const bool have = (t < 15);
        const size_t tb = (size_t)(t + 1) * 128 * DHH;

        // K prefetch (lands under QK)
        v8s kr[6];
        if (have) {
            #pragma unroll
            for (int i = 0; i < 6; ++i)
                kr[i] = *reinterpret_cast<const v8s*>(&Kg[tb + kgo[i]]);
        }

        // ---- QK + softmax + pack, per q-tile (S regs minimal)
        v8s pb[4];
        #pragma unroll
        for (int qt = 0; qt < 4; ++qt) {
            v4f s0, s1;
            #pragma unroll
            for (int i = 0; i < 4; ++i) { s0[i] = 0.0f; s1[i] = 0.0f; }
            __builtin_amdgcn_s_setprio(1);
            #pragma unroll
            for (int c = 0; c < 3; ++c) {
                const int kb = ((c * 4 + g4) * 128 + wv * 32 + l15) * 8;
                v8s kf0 = *reinterpret_cast<const v8s*>(&smem[kb]);
                v8s kf1 = *reinterpret_cast<const v8s*>(&smem[kb + 128]);
                s0 = __builtin_amdgcn_mfma_f32_16x16x32_bf16(kf0, qf[qt][c], s0, 0, 0, 0);
                s1 = __builtin_amdgcn_mfma_f32_16x16x32_bf16(kf1, qf[qt][c], s1, 0, 0, 0);
            }
            __builtin_amdgcn_s_setprio(0);
            float e00 = exp2f(s0[0]), e01 = exp2f(s0[1]),
                  e02 = exp2f(s0[2]), e03 = exp2f(s0[3]);
            float e10 = exp2f(s1[0]), e11 = exp2f(s1[1]),
                  e12 = exp2f(s1[2]), e13 = exp2f(s1[3]);
            ds4[qt] += ((e00 + e01) + (e02 + e03)) + ((e10 + e11) + (e12 + e13));
            pb[qt] = pack4(bfpair(e00, e01), bfpair(e02, e03),
                           bfpair(e10, e11), bfpair(e12, e13));
        }

        v8s vr[8];
        if (have) {
            __syncthreads();                       // all QK reads of Ks done
            #pragma unroll
            for (int i = 0; i < 6; ++i)
                *reinterpret_cast<v8s*>(&smem[klo[i]]) = kr[i];
            if (tid < 192) {                       // V prefetch (lands under PV)
                #pragma unroll
                for (int r = 0; r < 8; ++r)
                    vr[r] = *reinterpret_cast<const v8s*>(&Vg[tb + vgo + (size_t)r * DHH]);
            }
        }

        // ---- PV: A = V^T (pi-permuted), B = P
        __builtin_amdgcn_s_setprio(1);
        #pragma unroll
        for (int dt = 0; dt < 6; ++dt) {
            const ushort* vp = &smem[VTB + (dt * 16 + l15) * 136 + wv * 32 + g4 * 4];
            v8s va = load2x4_o16(vp);
            #pragma unroll
            for (int qt = 0; qt < 4; ++qt)
                of[dt][qt] = __builtin_amdgcn_mfma_f32_16x16x32_bf16(va, pb[qt], of[dt][qt], 0, 0, 0);
        }
        __builtin_amdgcn_s_setprio(0);

        if (have) {
            __syncthreads();                       // all PV reads of Vt done
            if (tid < 192) {
                #pragma unroll
                for (int j8 = 0; j8 < 8; ++j8) {
                    u32 w0 = (u32)(ushort)vr[0][j8] | ((u32)(ushort)vr[1][j8] << 16);
                    u32 w1 = (u32)(ushort)vr[2][j8] | ((u32)(ushort)vr[3][j8] << 16);
                    u32 w2 = (u32)(ushort)vr[4][j8] | ((u32)(ushort)vr[5][j8] << 16);
                    u32 w3 = (u32)(ushort)vr[6][j8] | ((u32)(ushort)vr[7][j8] << 16);
                    *reinterpret_cast<v8s*>(&smem[vlo + j8 * 136]) = pack4(w0, w1, w2, w3);
                }
            }
            __syncthreads();                       // stage visible for next QK
        }
    }

    // ---- epilogue: cross-wave reduction of O and denom
    #pragma unroll
    for (int qt = 0; qt < 4; ++qt) {
        ds4[qt] += __shfl_xor(ds4[qt], 16, 64);
        ds4[qt] += __shfl_xor(ds4[qt], 32, 64);
    }
    __syncthreads();                               // compute done; LDS reusable
    float* fsm = reinterpret_cast<float*>(smem);
    if (lane < 16) {
        #pragma unroll
        for (int qt = 0; qt < 4; ++qt)
            fsm[DSB + wv * 64 + qt * 16 + lane] = ds4[qt];
    }
    // sequential accumulate: waves 0..2 into Of[64][100]
    for (int w = 0; w < 3; ++w) {
        if (wv == w) {
            #pragma unroll
            for (int dt = 0; dt < 6; ++dt)
                #pragma unroll
                for (int qt = 0; qt < 4; ++qt) {
                    float* p = &fsm[(qt * 16 + l15) * 100 + dt * 16 + g4 * 4];
                    if (w == 0) {
                        *reinterpret_cast<v4f*>(p) = of[dt][qt];
                    } else {
                        v4f tmp = *reinterpret_cast<const v4f*>(p);
                        tmp += of[dt][qt];
                        *reinterpret_cast<v4f*>(p) = tmp;
                    }
                }
        }
        __syncthreads();
    }
    // wave 3: add own partial, normalize, store
    if (wv == 3) {
        float inv[4];
        #pragma unroll
        for (int qt = 0; qt < 4; ++qt) {
            const int q = qt * 16 + l15;
            inv[qt] = 1.0f / (fsm[DSB + q] + fsm[DSB + 64 + q] +
                              fsm[DSB + 128 + q] + fsm[DSB + 192 + q]);
        }
        #pragma unroll
        for (int dt = 0; dt < 6; ++dt)
            #pragma unroll
            for (int qt = 0; qt < 4; ++qt) {
                v4f tmp = *reinterpret_cast<const v4f*>(
                    &fsm[(qt * 16 + l15) * 100 + dt * 16 + g4 * 4]);
                tmp += of[dt][qt];
                const float iv = inv[qt];
                uint2 pk;
                pk.x = bfpair(tmp[0] * iv, tmp[1] * iv);
                pk.y = bfpair(tmp[2] * iv, tmp[3] * iv);
                *reinterpret_cast<uint2*>(
                    &attnout[((size_t)(b * NN + q0 + qt * 16 + l15)) * DM +
                             h * DHH + dt * 16 + g4 * 4]) = pk;
            }
    }
}

// ---------------------------------------------------------------------------
extern "C" void kernel_launch(void* const* d_in, const int* in_sizes, int n_in,
                              void* d_out, int out_size, void* d_ws, size_t ws_size,
                              hipStream_t stream)
{
    (void)in_sizes; (void)n_in; (void)out_size; (void)ws_size;
    const float* x    = (const float*)d_in[0];
    const float* Wqkv = (const float*)d_in[1];
    const float* bqkv = (const float*)d_in[2];
    const float* Wout = (const float*)d_in[3];
    const float* bout = (const float*)d_in[4];
    float* out = (float*)d_out;

    ushort* qkv   = (ushort*)d_ws;                       // [3][BH][NN][96] bf16
    ushort* ao    = qkv   + (size_t)3 * BH * NN * DHH;   // [8192][768] bf16
    ushort* xbf   = ao    + (size_t)MROWS * DM;          // [8192][768] bf16
    ushort* wqkvt = xbf   + (size_t)MROWS * DM;          // [2304][768] bf16
    ushort* woutt = wqkvt + (size_t)DM * NC_QKV;         // [768][768]  bf16

    dim3 blk(256);

    conv_bf16<<<dim3(MROWS * DM / 8 / 256), blk, 0, stream>>>(x, xbf, MROWS * DM / 8);
    convT_bf16<<<dim3(DM / 32, NC_QKV / 32), blk, 0, stream>>>(Wqkv, wqkvt, DM, NC_QKV);
    convT_bf16<<<dim3(DM / 32, DM / 32), blk, 0, stream>>>(Wout, woutt, DM, DM);

    gemm_mfma<1><<<dim3(MROWS / 128, NC_QKV / 128), blk, 0, stream>>>(
        xbf, wqkvt, bqkv, (void*)qkv, DM, NC_QKV);

    attn_mfma<<<dim3(32, 32), blk, 0, stream>>>(qkv, ao);

    gemm_mfma<0><<<dim3(MROWS / 128, DM / 128), blk, 0, stream>>>(
        ao, woutt, bout, (void*)out, DM, DM);
}

// Round 13
// 218.747 us; speedup vs baseline: 1.2345x; 1.2345x over previous
//
#include <hip/hip_runtime.h>
#include <hip/hip_bf16.h>
#include <math.h>

// Problem constants
#define BB      4
#define NN      2048
#define DM      768
#define NH      8
#define DHH     96
#define BH      (BB*NH)          // 32
#define MROWS   (BB*NN)          // 8192
#define NC_QKV  (3*DM)           // 2304

typedef short v4s  __attribute__((ext_vector_type(4)));
typedef short v8s  __attribute__((ext_vector_type(8)));
typedef float v4f  __attribute__((ext_vector_type(4)));
typedef float v16f __attribute__((ext_vector_type(16)));
typedef unsigned int u32;

// log2(e)/sqrt(96) folded into Q at QKV-GEMM epilogue
#define SCQ 0.14724599350930152f

static __device__ __forceinline__ ushort f2bf(float f) {
    __hip_bfloat16 h = __float2bfloat16(f);
    return *reinterpret_cast<ushort*>(&h);
}

static __device__ __forceinline__ void gload_lds16(const ushort* g, ushort* l) {
    __builtin_amdgcn_global_load_lds(
        (const __attribute__((address_space(1))) void*)g,
        (__attribute__((address_space(3))) void*)l, 16, 0, 0);
}

// two 8B LDS loads 32B apart -> one v8s A-fragment (k-permutation pi)
static __device__ __forceinline__ v8s load2x4_o16(const ushort* p) {
    union { v4s h[2]; v8s s; } x;
    x.h[0] = *reinterpret_cast<const v4s*>(p);
    x.h[1] = *reinterpret_cast<const v4s*>(p + 16);
    return x.s;
}

static __device__ __forceinline__ v8s pack4(u32 a, u32 b, u32 c, u32 d) {
    union { u32 u[4]; v8s s; } x;
    x.u[0] = a; x.u[1] = b; x.u[2] = c; x.u[3] = d;
    return x.s;
}
static __device__ __forceinline__ u32 bfpair(float lo, float hi) {
    return (u32)f2bf(lo) | ((u32)f2bf(hi) << 16);
}
static __device__ __forceinline__ u32 u16pair(ushort lo, ushort hi) {
    return (u32)lo | ((u32)hi << 16);
}

// ---------------------------------------------------------------------------
// fp32 -> bf16 elementwise (n8 = count/8)
// ---------------------------------------------------------------------------
__global__ __launch_bounds__(256)
void conv_bf16(const float* __restrict__ in, ushort* __restrict__ out, int n8)
{
    int i = blockIdx.x * 256 + threadIdx.x;
    if (i >= n8) return;
    const float4* p = reinterpret_cast<const float4*>(in) + (size_t)i * 2;
    float4 a = p[0], b = p[1];
    ushort r[8] = {f2bf(a.x), f2bf(a.y), f2bf(a.z), f2bf(a.w),
                   f2bf(b.x), f2bf(b.y), f2bf(b.z), f2bf(b.w)};
    *reinterpret_cast<v8s*>(out + (size_t)i * 8) = *reinterpret_cast<v8s*>(r);
}

// ---------------------------------------------------------------------------
// fp32 W[K][N] -> bf16 Wt[N][K] (tiled transpose)
// ---------------------------------------------------------------------------
__global__ __launch_bounds__(256)
void convT_bf16(const float* __restrict__ W, ushort* __restrict__ Wt, int K, int N)
{
    __shared__ ushort t[32][33];
    const int k0 = blockIdx.x * 32, n0 = blockIdx.y * 32;
    const int tx = threadIdx.x & 31, ty = threadIdx.x >> 5;
    #pragma unroll
    for (int r = ty; r < 32; r += 8)
        t[tx][r] = f2bf(W[(size_t)(k0 + r) * N + n0 + tx]);
    __syncthreads();
    #pragma unroll
    for (int r = ty; r < 32; r += 8)
        Wt[(size_t)(n0 + r) * K + k0 + tx] = t[r][tx];
}

// ---------------------------------------------------------------------------
// bf16 MFMA GEMM (round-6/7 form, harness-proven, unchanged)
// ---------------------------------------------------------------------------
template<int SCATTER>
__global__ __launch_bounds__(256)
void gemm_mfma(const ushort* __restrict__ A, const ushort* __restrict__ Bt,
               const float* __restrict__ bias, void* __restrict__ outp,
               int K, int Ncols)
{
    __shared__ ushort As[2][8192];   // [buf][8 kslots][128 rows][8]
    __shared__ ushort Bs[2][8192];

    const int tid  = threadIdx.x;
    const int lane = tid & 63;
    const int wv   = tid >> 6;
    const int l31  = lane & 31;
    const int lhi  = lane >> 5;
    const int wr   = wv >> 1, wc = wv & 1;

    const int ny   = gridDim.y;
    const int id   = blockIdx.y * gridDim.x + blockIdx.x;
    const int c8   = id & 7;
    const int j    = id >> 3;
    const int hy   = (j >= (ny >> 1) * 8) ? 1 : 0;
    const int w    = j - hy * (ny >> 1) * 8;
    const int bx   = c8 * 8 + (w & 7);
    const int by   = hy * (ny >> 1) + (w >> 3);
    const int row0 = bx * 128;
    const int col0 = by * 128;

    v16f acc[2][2];
    #pragma unroll
    for (int mi = 0; mi < 2; ++mi)
        #pragma unroll
        for (int nj = 0; nj < 2; ++nj)
            #pragma unroll
            for (int i = 0; i < 16; ++i) acc[mi][nj][i] = 0.0f;

#define STAGE_G(bsel, kk) do {                                                  \
    _Pragma("unroll")                                                           \
    for (int c = 0; c < 4; ++c) {                                               \
        const int g   = c * 4 + wv;                                             \
        const int idx = g * 64 + lane;                                          \
        const int ss  = idx >> 7, rr = idx & 127;                               \
        gload_lds16(&A [(size_t)(row0 + rr) * K + (kk) + ss * 8],               \
                    &As[bsel][g * 512]);                                        \
        gload_lds16(&Bt[(size_t)(col0 + rr) * K + (kk) + ss * 8],               \
                    &Bs[bsel][g * 512]);                                        \
    }                                                                           \
} while (0)

    STAGE_G(0, 0);
    __syncthreads();

    const int nk = K >> 6;
    for (int t = 0; t < nk; ++t) {
        const int cur = t & 1;
        if (t + 1 < nk) STAGE_G(cur ^ 1, (t + 1) << 6);

        #pragma unroll
        for (int s16 = 0; s16 < 4; ++s16) {
            const int ks = s16 * 2 + lhi;
            v8s a0 = *reinterpret_cast<const v8s*>(&As[cur][(size_t)(ks * 128 + 64 * wr + l31) * 8]);
            v8s a1 = *reinterpret_cast<const v8s*>(&As[cur][(size_t)(ks * 128 + 64 * wr + 32 + l31) * 8]);
            v8s b0 = *reinterpret_cast<const v8s*>(&Bs[cur][(size_t)(ks * 128 + 64 * wc + l31) * 8]);
            v8s b1 = *reinterpret_cast<const v8s*>(&Bs[cur][(size_t)(ks * 128 + 64 * wc + 32 + l31) * 8]);
            acc[0][0] = __builtin_amdgcn_mfma_f32_32x32x16_bf16(a0, b0, acc[0][0], 0, 0, 0);
            acc[0][1] = __builtin_amdgcn_mfma_f32_32x32x16_bf16(a0, b1, acc[0][1], 0, 0, 0);
            acc[1][0] = __builtin_amdgcn_mfma_f32_32x32x16_bf16(a1, b0, acc[1][0], 0, 0, 0);
            acc[1][1] = __builtin_amdgcn_mfma_f32_32x32x16_bf16(a1, b1, acc[1][1], 0, 0, 0);
        }
        __syncthreads();
    }
#undef STAGE_G

    #pragma unroll
    for (int nj = 0; nj < 2; ++nj) {
        const int c = col0 + 64 * wc + 32 * nj + l31;
        const float bv = bias[c];
        #pragma unroll
        for (int mi = 0; mi < 2; ++mi) {
            #pragma unroll
            for (int r = 0; r < 16; ++r) {
                const int m = row0 + 64 * wr + 32 * mi + (r & 3) + 8 * (r >> 2) + 4 * lhi;
                float v = acc[mi][nj][r] + bv;
                if (SCATTER) {
                    const int s   = c / DM;
                    const int rem = c - s * DM;
                    const int h   = rem / DHH;
                    const int d   = rem - h * DHH;
                    const int b   = m >> 11;
                    const int n   = m & (NN - 1);
                    if (s == 0) v *= SCQ;
                    ((ushort*)outp)[((size_t)(s * BH + b * NH + h) * NN + n) * DHH + d] = f2bf(v);
                } else {
                    ((float*)outp)[(size_t)m * Ncols + c] = v;
                }
            }
        }
    }
}

// ---------------------------------------------------------------------------
// MFMA bf16 flash attention: round-11 kernel (16x16x32, 4 waves/SIMD,
// exchange-free P via pi(g4,i)=g4*4+(i&3)+16*(i>>2), single-buffered K/V,
// read->barrier->write->barrier handoff) with ONE change: V-transpose
// staging in REGISTERS. Threads 0-95 each own an (8kv x 8d) block: 8 v8s
// global loads, pack pairs, 8 ds_write_b128 rows -> V-write DS ops drop 8x
// (6144 scalar b16 -> 768 b128 per tile). Vt pad 68->72 for 16B-aligned
// rows (144B stride = round-7's benign 2-way pattern).
// ---------------------------------------------------------------------------
__global__ __launch_bounds__(256, 4)
void attn_mfma(const ushort* __restrict__ qkv, ushort* __restrict__ attnout)
{
    __shared__ ushort Ks[6144];        // [g=d/8:12][kv=64][8]
    __shared__ ushort Vt[96][72];      // [d][kv], pad 72 (16B-aligned rows)

    const int tid  = threadIdx.x;
    const int lane = tid & 63;
    const int wv   = tid >> 6;          // 0..3
    const int l15  = lane & 15;
    const int g4   = lane >> 4;         // 0..3

    // bh-clustered XCD swizzle (grid = (32 qt, 32 bh)): 4 bh per XCD
    const int id   = blockIdx.y * gridDim.x + blockIdx.x;
    const int c8   = id & 7;
    const int j    = id >> 3;            // 0..127
    const int bh   = c8 * 4 + (j & 3);
    const int qt   = j >> 2;             // 0..31
    const int q0   = qt * 64;
    const int b    = bh >> 3, h = bh & 7;

    const ushort* Qg = qkv + (size_t)bh * NN * DHH;
    const ushort* Kg = qkv + ((size_t)BH + bh) * NN * DHH;
    const ushort* Vg = qkv + ((size_t)2 * BH + bh) * NN * DHH;

    // Q B-fragments (pre-scaled by SCQ): col=q=l15, k=d=c*32+g4*8+i
    const int qrow = q0 + wv * 16 + l15;
    v8s qf[3];
    #pragma unroll
    for (int c = 0; c < 3; ++c)
        qf[c] = *reinterpret_cast<const v8s*>(&Qg[(size_t)qrow * DHH + c * 32 + g4 * 8]);

    v4f o[6];
    #pragma unroll
    for (int dt = 0; dt < 6; ++dt)
        #pragma unroll
        for (int i = 0; i < 4; ++i) o[dt][i] = 0.0f;
    float ds = 0.0f;

    // V-transpose task (threads 0..95): kv-octet ko, d-octet do8
    const int  ko    = tid & 7;
    const int  do8   = tid >> 3;          // 0..11 valid when vtask
    const bool vtask = (tid < 96);

    // ---- prologue: stage tile 0 -> LDS
    {
        const size_t rowb = (size_t)lane * DHH;
        v8s kr[3];
        #pragma unroll
        for (int i = 0; i < 3; ++i)
            kr[i] = *reinterpret_cast<const v8s*>(&Kg[rowb + (wv * 3 + i) * 8]);
        v8s vr[8];
        if (vtask) {
            #pragma unroll
            for (int r = 0; r < 8; ++r)
                vr[r] = *reinterpret_cast<const v8s*>(&Vg[(size_t)(ko * 8 + r) * DHH + do8 * 8]);
        }
        #pragma unroll
        for (int i = 0; i < 3; ++i)
            *reinterpret_cast<v8s*>(&Ks[(wv * 3 + i) * 512 + lane * 8]) = kr[i];
        if (vtask) {
            #pragma unroll
            for (int j8 = 0; j8 < 8; ++j8) {
                v8s row = pack4(u16pair((ushort)vr[0][j8], (ushort)vr[1][j8]),
                                u16pair((ushort)vr[2][j8], (ushort)vr[3][j8]),
                                u16pair((ushort)vr[4][j8], (ushort)vr[5][j8]),
                                u16pair((ushort)vr[6][j8], (ushort)vr[7][j8]));
                *reinterpret_cast<v8s*>(&Vt[do8 * 8 + j8][ko * 8]) = row;
            }
        }
    }
    __syncthreads();

    for (int t = 0; t < 32; ++t) {
        // issue next-tile global->reg loads early (land under compute)
        v8s kr0, kr1, kr2, vr[8];
        if (t < 31) {
            const size_t rowb = (size_t)((t + 1) * 64 + lane) * DHH;
            kr0 = *reinterpret_cast<const v8s*>(&Kg[rowb + (wv * 3 + 0) * 8]);
            kr1 = *reinterpret_cast<const v8s*>(&Kg[rowb + (wv * 3 + 1) * 8]);
            kr2 = *reinterpret_cast<const v8s*>(&Kg[rowb + (wv * 3 + 2) * 8]);
            if (vtask) {
                const size_t vb = (size_t)((t + 1) * 64 + ko * 8) * DHH + do8 * 8;
                #pragma unroll
                for (int r = 0; r < 8; ++r)
                    vr[r] = *reinterpret_cast<const v8s*>(&Vg[vb + (size_t)r * DHH]);
            }
        }

        // two 32-kv halves: QK (2 S-tiles) -> softmax -> PV (6 d-tiles)
        #pragma unroll
        for (int th = 0; th < 2; ++th) {
            v4f s0, s1;
            #pragma unroll
            for (int i = 0; i < 4; ++i) { s0[i] = 0.0f; s1[i] = 0.0f; }
            __builtin_amdgcn_s_setprio(1);
            #pragma unroll
            for (int c = 0; c < 3; ++c) {
                v8s kf0 = *reinterpret_cast<const v8s*>(
                    &Ks[((c * 4 + g4) * 64 + (th * 2 + 0) * 16 + l15) * 8]);
                v8s kf1 = *reinterpret_cast<const v8s*>(
                    &Ks[((c * 4 + g4) * 64 + (th * 2 + 1) * 16 + l15) * 8]);
                s0 = __builtin_amdgcn_mfma_f32_16x16x32_bf16(kf0, qf[c], s0, 0, 0, 0);
                s1 = __builtin_amdgcn_mfma_f32_16x16x32_bf16(kf1, qf[c], s1, 0, 0, 0);
            }
            __builtin_amdgcn_s_setprio(0);

            // exp + denom; lane holds kv = th*32 + {g4*4+j, 16+g4*4+j}, q=l15
            float e0[4], e1[4];
            #pragma unroll
            for (int r = 0; r < 4; ++r) {
                e0[r] = exp2f(s0[r]);
                e1[r] = exp2f(s1[r]);
                ds += e0[r] + e1[r];
            }
            // B-frag slots i: kv_local32 = g4*4 + (i&3) + 16*(i>>2)
            v8s pf = pack4(bfpair(e0[0], e0[1]), bfpair(e0[2], e0[3]),
                           bfpair(e1[0], e1[1]), bfpair(e1[2], e1[3]));

            // PV: A = V^T with the same k-permutation (8B reads at +0/+32B)
            __builtin_amdgcn_s_setprio(1);
            #pragma unroll
            for (int dt = 0; dt < 6; ++dt) {
                const ushort* vp = &Vt[dt * 16 + l15][th * 32 + g4 * 4];
                v8s va = load2x4_o16(vp);
                o[dt] = __builtin_amdgcn_mfma_f32_16x16x32_bf16(va, pf, o[dt], 0, 0, 0);
            }
            __builtin_amdgcn_s_setprio(0);
        }

        // single-buffer handoff: reads done -> write next tile -> visible
        if (t < 31) {
            __syncthreads();
            *reinterpret_cast<v8s*>(&Ks[(wv * 3 + 0) * 512 + lane * 8]) = kr0;
            *reinterpret_cast<v8s*>(&Ks[(wv * 3 + 1) * 512 + lane * 8]) = kr1;
            *reinterpret_cast<v8s*>(&Ks[(wv * 3 + 2) * 512 + lane * 8]) = kr2;
            if (vtask) {
                #pragma unroll
                for (int j8 = 0; j8 < 8; ++j8) {
                    v8s row = pack4(u16pair((ushort)vr[0][j8], (ushort)vr[1][j8]),
                                    u16pair((ushort)vr[2][j8], (ushort)vr[3][j8]),
                                    u16pair((ushort)vr[4][j8], (ushort)vr[5][j8]),
                                    u16pair((ushort)vr[6][j8], (ushort)vr[7][j8]));
                    *reinterpret_cast<v8s*>(&Vt[do8 * 8 + j8][ko * 8]) = row;
                }
            }
            __syncthreads();
        }
    }

    // denominator: combine the 4 lane-groups sharing q=l15
    ds += __shfl_xor(ds, 16, 64);
    ds += __shfl_xor(ds, 32, 64);
    const float inv = 1.0f / ds;

    // write O^T: lane q = l15 -> n; regs = d (4 consecutive per dt -> 8B)
    const int n = q0 + wv * 16 + l15;
    ushort* orow = attnout + ((size_t)(b * NN + n)) * DM + h * DHH;
    #pragma unroll
    for (int dt = 0; dt < 6; ++dt) {
        const int d0 = dt * 16 + g4 * 4;
        uint2 pk;
        pk.x = bfpair(o[dt][0] * inv, o[dt][1] * inv);
        pk.y = bfpair(o[dt][2] * inv, o[dt][3] * inv);
        *reinterpret_cast<uint2*>(&orow[d0]) = pk;
    }
}

// ---------------------------------------------------------------------------
extern "C" void kernel_launch(void* const* d_in, const int* in_sizes, int n_in,
                              void* d_out, int out_size, void* d_ws, size_t ws_size,
                              hipStream_t stream)
{
    (void)in_sizes; (void)n_in; (void)out_size; (void)ws_size;
    const float* x    = (const float*)d_in[0];
    const float* Wqkv = (const float*)d_in[1];
    const float* bqkv = (const float*)d_in[2];
    const float* Wout = (const float*)d_in[3];
    const float* bout = (const float*)d_in[4];
    float* out = (float*)d_out;

    ushort* qkv   = (ushort*)d_ws;                       // [3][BH][NN][96] bf16
    ushort* ao    = qkv   + (size_t)3 * BH * NN * DHH;   // [8192][768] bf16
    ushort* xbf   = ao    + (size_t)MROWS * DM;          // [8192][768] bf16
    ushort* wqkvt = xbf   + (size_t)MROWS * DM;          // [2304][768] bf16
    ushort* woutt = wqkvt + (size_t)DM * NC_QKV;         // [768][768]  bf16

    dim3 blk(256);

    conv_bf16<<<dim3(MROWS * DM / 8 / 256), blk, 0, stream>>>(x, xbf, MROWS * DM / 8);
    convT_bf16<<<dim3(DM / 32, NC_QKV / 32), blk, 0, stream>>>(Wqkv, wqkvt, DM, NC_QKV);
    convT_bf16<<<dim3(DM / 32, DM / 32), blk, 0, stream>>>(Wout, woutt, DM, DM);

    gemm_mfma<1><<<dim3(MROWS / 128, NC_QKV / 128), blk, 0, stream>>>(
        xbf, wqkvt, bqkv, (void*)qkv, DM, NC_QKV);

    attn_mfma<<<dim3(32, 32), blk, 0, stream>>>(qkv, ao);

    gemm_mfma<0><<<dim3(MROWS / 128, DM / 128), blk, 0, stream>>>(
        ao, woutt, bout, (void*)out, DM, DM);
}

// Round 14
// 204.520 us; speedup vs baseline: 1.3204x; 1.0696x over previous
//
#include <hip/hip_runtime.h>
#include <hip/hip_bf16.h>
#include <math.h>

// Problem constants
#define BB      4
#define NN      2048
#define DM      768
#define NH      8
#define DHH     96
#define BH      (BB*NH)          // 32
#define MROWS   (BB*NN)          // 8192
#define NC_QKV  (3*DM)           // 2304

typedef short v4s  __attribute__((ext_vector_type(4)));
typedef short v8s  __attribute__((ext_vector_type(8)));
typedef float v4f  __attribute__((ext_vector_type(4)));
typedef float v16f __attribute__((ext_vector_type(16)));
typedef unsigned int u32;

// log2(e)/sqrt(96) folded into Q at QKV-GEMM epilogue
#define SCQ 0.14724599350930152f

static __device__ __forceinline__ ushort f2bf(float f) {
    __hip_bfloat16 h = __float2bfloat16(f);
    return *reinterpret_cast<ushort*>(&h);
}

static __device__ __forceinline__ void gload_lds16(const ushort* g, ushort* l) {
    __builtin_amdgcn_global_load_lds(
        (const __attribute__((address_space(1))) void*)g,
        (__attribute__((address_space(3))) void*)l, 16, 0, 0);
}

// two 8B LDS loads 32B apart -> one v8s A-fragment (k-permutation pi)
static __device__ __forceinline__ v8s load2x4_o16(const ushort* p) {
    union { v4s h[2]; v8s s; } x;
    x.h[0] = *reinterpret_cast<const v4s*>(p);
    x.h[1] = *reinterpret_cast<const v4s*>(p + 16);
    return x.s;
}

static __device__ __forceinline__ v8s pack4(u32 a, u32 b, u32 c, u32 d) {
    union { u32 u[4]; v8s s; } x;
    x.u[0] = a; x.u[1] = b; x.u[2] = c; x.u[3] = d;
    return x.s;
}
static __device__ __forceinline__ u32 bfpair(float lo, float hi) {
    return (u32)f2bf(lo) | ((u32)f2bf(hi) << 16);
}

// ---------------------------------------------------------------------------
// fp32 -> bf16 elementwise (n8 = count/8)
// ---------------------------------------------------------------------------
__global__ __launch_bounds__(256)
void conv_bf16(const float* __restrict__ in, ushort* __restrict__ out, int n8)
{
    int i = blockIdx.x * 256 + threadIdx.x;
    if (i >= n8) return;
    const float4* p = reinterpret_cast<const float4*>(in) + (size_t)i * 2;
    float4 a = p[0], b = p[1];
    ushort r[8] = {f2bf(a.x), f2bf(a.y), f2bf(a.z), f2bf(a.w),
                   f2bf(b.x), f2bf(b.y), f2bf(b.z), f2bf(b.w)};
    *reinterpret_cast<v8s*>(out + (size_t)i * 8) = *reinterpret_cast<v8s*>(r);
}

// ---------------------------------------------------------------------------
// fp32 W[K][N] -> bf16 Wt[N][K] (tiled transpose)
// ---------------------------------------------------------------------------
__global__ __launch_bounds__(256)
void convT_bf16(const float* __restrict__ W, ushort* __restrict__ Wt, int K, int N)
{
    __shared__ ushort t[32][33];
    const int k0 = blockIdx.x * 32, n0 = blockIdx.y * 32;
    const int tx = threadIdx.x & 31, ty = threadIdx.x >> 5;
    #pragma unroll
    for (int r = ty; r < 32; r += 8)
        t[tx][r] = f2bf(W[(size_t)(k0 + r) * N + n0 + tx]);
    __syncthreads();
    #pragma unroll
    for (int r = ty; r < 32; r += 8)
        Wt[(size_t)(n0 + r) * K + k0 + tx] = t[r][tx];
}

// ---------------------------------------------------------------------------
// bf16 MFMA GEMM (round-6/7 form, harness-proven, unchanged)
// ---------------------------------------------------------------------------
template<int SCATTER>
__global__ __launch_bounds__(256)
void gemm_mfma(const ushort* __restrict__ A, const ushort* __restrict__ Bt,
               const float* __restrict__ bias, void* __restrict__ outp,
               int K, int Ncols)
{
    __shared__ ushort As[2][8192];   // [buf][8 kslots][128 rows][8]
    __shared__ ushort Bs[2][8192];

    const int tid  = threadIdx.x;
    const int lane = tid & 63;
    const int wv   = tid >> 6;
    const int l31  = lane & 31;
    const int lhi  = lane >> 5;
    const int wr   = wv >> 1, wc = wv & 1;

    const int ny   = gridDim.y;
    const int id   = blockIdx.y * gridDim.x + blockIdx.x;
    const int c8   = id & 7;
    const int j    = id >> 3;
    const int hy   = (j >= (ny >> 1) * 8) ? 1 : 0;
    const int w    = j - hy * (ny >> 1) * 8;
    const int bx   = c8 * 8 + (w & 7);
    const int by   = hy * (ny >> 1) + (w >> 3);
    const int row0 = bx * 128;
    const int col0 = by * 128;

    v16f acc[2][2];
    #pragma unroll
    for (int mi = 0; mi < 2; ++mi)
        #pragma unroll
        for (int nj = 0; nj < 2; ++nj)
            #pragma unroll
            for (int i = 0; i < 16; ++i) acc[mi][nj][i] = 0.0f;

#define STAGE_G(bsel, kk) do {                                                  \
    _Pragma("unroll")                                                           \
    for (int c = 0; c < 4; ++c) {                                               \
        const int g   = c * 4 + wv;                                             \
        const int idx = g * 64 + lane;                                          \
        const int ss  = idx >> 7, rr = idx & 127;                               \
        gload_lds16(&A [(size_t)(row0 + rr) * K + (kk) + ss * 8],               \
                    &As[bsel][g * 512]);                                        \
        gload_lds16(&Bt[(size_t)(col0 + rr) * K + (kk) + ss * 8],               \
                    &Bs[bsel][g * 512]);                                        \
    }                                                                           \
} while (0)

    STAGE_G(0, 0);
    __syncthreads();

    const int nk = K >> 6;
    for (int t = 0; t < nk; ++t) {
        const int cur = t & 1;
        if (t + 1 < nk) STAGE_G(cur ^ 1, (t + 1) << 6);

        #pragma unroll
        for (int s16 = 0; s16 < 4; ++s16) {
            const int ks = s16 * 2 + lhi;
            v8s a0 = *reinterpret_cast<const v8s*>(&As[cur][(size_t)(ks * 128 + 64 * wr + l31) * 8]);
            v8s a1 = *reinterpret_cast<const v8s*>(&As[cur][(size_t)(ks * 128 + 64 * wr + 32 + l31) * 8]);
            v8s b0 = *reinterpret_cast<const v8s*>(&Bs[cur][(size_t)(ks * 128 + 64 * wc + l31) * 8]);
            v8s b1 = *reinterpret_cast<const v8s*>(&Bs[cur][(size_t)(ks * 128 + 64 * wc + 32 + l31) * 8]);
            acc[0][0] = __builtin_amdgcn_mfma_f32_32x32x16_bf16(a0, b0, acc[0][0], 0, 0, 0);
            acc[0][1] = __builtin_amdgcn_mfma_f32_32x32x16_bf16(a0, b1, acc[0][1], 0, 0, 0);
            acc[1][0] = __builtin_amdgcn_mfma_f32_32x32x16_bf16(a1, b0, acc[1][0], 0, 0, 0);
            acc[1][1] = __builtin_amdgcn_mfma_f32_32x32x16_bf16(a1, b1, acc[1][1], 0, 0, 0);
        }
        __syncthreads();
    }
#undef STAGE_G

    #pragma unroll
    for (int nj = 0; nj < 2; ++nj) {
        const int c = col0 + 64 * wc + 32 * nj + l31;
        const float bv = bias[c];
        #pragma unroll
        for (int mi = 0; mi < 2; ++mi) {
            #pragma unroll
            for (int r = 0; r < 16; ++r) {
                const int m = row0 + 64 * wr + 32 * mi + (r & 3) + 8 * (r >> 2) + 4 * lhi;
                float v = acc[mi][nj][r] + bv;
                if (SCATTER) {
                    const int s   = c / DM;
                    const int rem = c - s * DM;
                    const int h   = rem / DHH;
                    const int d   = rem - h * DHH;
                    const int b   = m >> 11;
                    const int n   = m & (NN - 1);
                    if (s == 0) v *= SCQ;
                    ((ushort*)outp)[((size_t)(s * BH + b * NH + h) * NN + n) * DHH + d] = f2bf(v);
                } else {
                    ((float*)outp)[(size_t)m * Ncols + c] = v;
                }
            }
        }
    }
}

// ---------------------------------------------------------------------------
// MFMA bf16 flash attention: round-11 kernel (16x16x32, exchange-free P via
// pi(g4,i)=g4*4+(i&3)+16*(i>>2), single-buffered K/V with r11's EXACT
// layout/staging -- scalar-b16 V transpose, Vt[96][68], conflicts==0) with
// ONE structural change: TWO q-tiles per wave (block = 128 q rows). Every
// K-fragment and V-fragment LDS read now feeds 2 MFMAs (one per q-tile) and
// block count halves -> total DS ops halve (DS pipe was the measured
// bottleneck: r11 DS-cycle model == 99us measured). LDS addresses, staging
// pattern, and barrier structure are byte-identical to r11.
// ---------------------------------------------------------------------------
__global__ __launch_bounds__(256, 2)
void attn_mfma(const ushort* __restrict__ qkv, ushort* __restrict__ attnout)
{
    __shared__ ushort Ks[6144];        // [g=d/8:12][kv=64][8]
    __shared__ ushort Vt[96][68];      // [d][kv], pad 68 (r11-proven, 0 confl)

    const int tid  = threadIdx.x;
    const int lane = tid & 63;
    const int wv   = tid >> 6;          // 0..3
    const int l15  = lane & 15;
    const int g4   = lane >> 4;         // 0..3

    // bh-clustered XCD swizzle (grid = (16 qblk, 32 bh)): 4 bh per XCD
    const int id   = blockIdx.y * gridDim.x + blockIdx.x;   // 0..511
    const int c8   = id & 7;
    const int j    = id >> 3;            // 0..63
    const int bh   = c8 * 4 + (j & 3);
    const int qblk = j >> 2;             // 0..15
    const int q0   = qblk * 128;
    const int b    = bh >> 3, h = bh & 7;

    const ushort* Qg = qkv + (size_t)bh * NN * DHH;
    const ushort* Kg = qkv + ((size_t)BH + bh) * NN * DHH;
    const ushort* Vg = qkv + ((size_t)2 * BH + bh) * NN * DHH;

    // Q B-fragments (pre-scaled by SCQ), 2 q-tiles per wave:
    // q row = q0 + wv*32 + qt*16 + l15, k = d = c*32 + g4*8 + i
    v8s qf[2][3];
    #pragma unroll
    for (int qt = 0; qt < 2; ++qt)
        #pragma unroll
        for (int c = 0; c < 3; ++c)
            qf[qt][c] = *reinterpret_cast<const v8s*>(
                &Qg[(size_t)(q0 + wv * 32 + qt * 16 + l15) * DHH + c * 32 + g4 * 8]);

    v4f o[2][6];
    #pragma unroll
    for (int qt = 0; qt < 2; ++qt)
        #pragma unroll
        for (int dt = 0; dt < 6; ++dt)
            #pragma unroll
            for (int i = 0; i < 4; ++i) o[qt][dt][i] = 0.0f;
    float ds[2] = {0.0f, 0.0f};

    // ---- prologue: stage tile 0 -> LDS (r11-exact)
    {
        const size_t rowb = (size_t)lane * DHH;
        v8s kr[3], vr[3];
        #pragma unroll
        for (int i = 0; i < 3; ++i) {
            kr[i] = *reinterpret_cast<const v8s*>(&Kg[rowb + (wv * 3 + i) * 8]);
            vr[i] = *reinterpret_cast<const v8s*>(&Vg[rowb + (i * 4 + wv) * 8]);
        }
        #pragma unroll
        for (int i = 0; i < 3; ++i) {
            *reinterpret_cast<v8s*>(&Ks[(wv * 3 + i) * 512 + lane * 8]) = kr[i];
            #pragma unroll
            for (int jj = 0; jj < 8; ++jj)
                Vt[(i * 4 + wv) * 8 + jj][lane] = (ushort)vr[i][jj];
        }
    }
    __syncthreads();

    for (int t = 0; t < 32; ++t) {
        // issue next-tile global->reg loads early (land under compute)
        v8s kr0, kr1, kr2, vr0, vr1, vr2;
        if (t < 31) {
            const size_t rowb = (size_t)((t + 1) * 64 + lane) * DHH;
            kr0 = *reinterpret_cast<const v8s*>(&Kg[rowb + (wv * 3 + 0) * 8]);
            kr1 = *reinterpret_cast<const v8s*>(&Kg[rowb + (wv * 3 + 1) * 8]);
            kr2 = *reinterpret_cast<const v8s*>(&Kg[rowb + (wv * 3 + 2) * 8]);
            vr0 = *reinterpret_cast<const v8s*>(&Vg[rowb + (0 * 4 + wv) * 8]);
            vr1 = *reinterpret_cast<const v8s*>(&Vg[rowb + (1 * 4 + wv) * 8]);
            vr2 = *reinterpret_cast<const v8s*>(&Vg[rowb + (2 * 4 + wv) * 8]);
        }

        // two 32-kv halves: QK (shared K-frags, 2 qt) -> softmax -> PV
        #pragma unroll
        for (int th = 0; th < 2; ++th) {
            v4f s00, s01, s10, s11;   // [qt][kv-subtile]
            #pragma unroll
            for (int i = 0; i < 4; ++i) {
                s00[i] = 0.0f; s01[i] = 0.0f; s10[i] = 0.0f; s11[i] = 0.0f;
            }
            __builtin_amdgcn_s_setprio(1);
            #pragma unroll
            for (int c = 0; c < 3; ++c) {
                v8s kf0 = *reinterpret_cast<const v8s*>(
                    &Ks[((c * 4 + g4) * 64 + (th * 2 + 0) * 16 + l15) * 8]);
                v8s kf1 = *reinterpret_cast<const v8s*>(
                    &Ks[((c * 4 + g4) * 64 + (th * 2 + 1) * 16 + l15) * 8]);
                s00 = __builtin_amdgcn_mfma_f32_16x16x32_bf16(kf0, qf[0][c], s00, 0, 0, 0);
                s01 = __builtin_amdgcn_mfma_f32_16x16x32_bf16(kf1, qf[0][c], s01, 0, 0, 0);
                s10 = __builtin_amdgcn_mfma_f32_16x16x32_bf16(kf0, qf[1][c], s10, 0, 0, 0);
                s11 = __builtin_amdgcn_mfma_f32_16x16x32_bf16(kf1, qf[1][c], s11, 0, 0, 0);
            }
            __builtin_amdgcn_s_setprio(0);

            // exp + denom + pack per q-tile
            v8s pf[2];
            #pragma unroll
            for (int qt = 0; qt < 2; ++qt) {
                const v4f& sa = qt ? s10 : s00;
                const v4f& sb = qt ? s11 : s01;
                float e0[4], e1[4];
                #pragma unroll
                for (int r = 0; r < 4; ++r) {
                    e0[r] = exp2f(sa[r]);
                    e1[r] = exp2f(sb[r]);
                    ds[qt] += e0[r] + e1[r];
                }
                pf[qt] = pack4(bfpair(e0[0], e0[1]), bfpair(e0[2], e0[3]),
                               bfpair(e1[0], e1[1]), bfpair(e1[2], e1[3]));
            }

            // PV: shared V-frag read feeds both q-tiles
            __builtin_amdgcn_s_setprio(1);
            #pragma unroll
            for (int dt = 0; dt < 6; ++dt) {
                const ushort* vp = &Vt[dt * 16 + l15][th * 32 + g4 * 4];
                v8s va = load2x4_o16(vp);
                o[0][dt] = __builtin_amdgcn_mfma_f32_16x16x32_bf16(va, pf[0], o[0][dt], 0, 0, 0);
                o[1][dt] = __builtin_amdgcn_mfma_f32_16x16x32_bf16(va, pf[1], o[1][dt], 0, 0, 0);
            }
            __builtin_amdgcn_s_setprio(0);
        }

        // single-buffer handoff: reads done -> write next tile -> visible
        if (t < 31) {
            __syncthreads();
            *reinterpret_cast<v8s*>(&Ks[(wv * 3 + 0) * 512 + lane * 8]) = kr0;
            *reinterpret_cast<v8s*>(&Ks[(wv * 3 + 1) * 512 + lane * 8]) = kr1;
            *reinterpret_cast<v8s*>(&Ks[(wv * 3 + 2) * 512 + lane * 8]) = kr2;
            #pragma unroll
            for (int jj = 0; jj < 8; ++jj) Vt[(0 * 4 + wv) * 8 + jj][lane] = (ushort)vr0[jj];
            #pragma unroll
            for (int jj = 0; jj < 8; ++jj) Vt[(1 * 4 + wv) * 8 + jj][lane] = (ushort)vr1[jj];
            #pragma unroll
            for (int jj = 0; jj < 8; ++jj) Vt[(2 * 4 + wv) * 8 + jj][lane] = (ushort)vr2[jj];
            __syncthreads();
        }
    }

    // epilogue per q-tile: reduce denom across the 4 lane-groups, store O^T
    #pragma unroll
    for (int qt = 0; qt < 2; ++qt) {
        float d = ds[qt];
        d += __shfl_xor(d, 16, 64);
        d += __shfl_xor(d, 32, 64);
        const float inv = 1.0f / d;
        const int n = q0 + wv * 32 + qt * 16 + l15;
        ushort* orow = attnout + ((size_t)(b * NN + n)) * DM + h * DHH;
        #pragma unroll
        for (int dt = 0; dt < 6; ++dt) {
            const int d0 = dt * 16 + g4 * 4;
            uint2 pk;
            pk.x = bfpair(o[qt][dt][0] * inv, o[qt][dt][1] * inv);
            pk.y = bfpair(o[qt][dt][2] * inv, o[qt][dt][3] * inv);
            *reinterpret_cast<uint2*>(&orow[d0]) = pk;
        }
    }
}

// ---------------------------------------------------------------------------
extern "C" void kernel_launch(void* const* d_in, const int* in_sizes, int n_in,
                              void* d_out, int out_size, void* d_ws, size_t ws_size,
                              hipStream_t stream)
{
    (void)in_sizes; (void)n_in; (void)out_size; (void)ws_size;
    const float* x    = (const float*)d_in[0];
    const float* Wqkv = (const float*)d_in[1];
    const float* bqkv = (const float*)d_in[2];
    const float* Wout = (const float*)d_in[3];
    const float* bout = (const float*)d_in[4];
    float* out = (float*)d_out;

    ushort* qkv   = (ushort*)d_ws;                       // [3][BH][NN][96] bf16
    ushort* ao    = qkv   + (size_t)3 * BH * NN * DHH;   // [8192][768] bf16
    ushort* xbf   = ao    + (size_t)MROWS * DM;          // [8192][768] bf16
    ushort* wqkvt = xbf   + (size_t)MROWS * DM;          // [2304][768] bf16
    ushort* woutt = wqkvt + (size_t)DM * NC_QKV;         // [768][768]  bf16

    dim3 blk(256);

    conv_bf16<<<dim3(MROWS * DM / 8 / 256), blk, 0, stream>>>(x, xbf, MROWS * DM / 8);
    convT_bf16<<<dim3(DM / 32, NC_QKV / 32), blk, 0, stream>>>(Wqkv, wqkvt, DM, NC_QKV);
    convT_bf16<<<dim3(DM / 32, DM / 32), blk, 0, stream>>>(Wout, woutt, DM, DM);

    gemm_mfma<1><<<dim3(MROWS / 128, NC_QKV / 128), blk, 0, stream>>>(
        xbf, wqkvt, bqkv, (void*)qkv, DM, NC_QKV);

    attn_mfma<<<dim3(16, 32), blk, 0, stream>>>(qkv, ao);

    gemm_mfma<0><<<dim3(MROWS / 128, DM / 128), blk, 0, stream>>>(
        ao, woutt, bout, (void*)out, DM, DM);
}